// Round 4
// baseline (167.768 us; speedup 1.0000x reference)
//
#include <hip/hip_runtime.h>

#define N_    64
#define HW_   240
#define H1_   120
#define H2_   60
#define C0_   3
#define C1_   32
#define C2_   64
#define C3_   128
#define HEAD_ 1280

typedef unsigned short US;
typedef short bf16x8 __attribute__((ext_vector_type(8)));
typedef float f32x16 __attribute__((ext_vector_type(16)));

__device__ __forceinline__ US f2bf(float f) {
  union { float f; unsigned u; } v; v.f = f;
  unsigned r = v.u + 0x7FFF + ((v.u >> 16) & 1);  // RNE
  return (US)(r >> 16);
}

// ---------------------------------------------------------------------------
// K0 (R17): weight prep only — h1q no longer exists in global memory.
// w1 -> wt1 [ky][kx][oc][ic] bf16; w2 -> wt2 [oc][ic] bf16;
// w_stem -> wt0 [oc][k32] bf16 (k>=27 zero); zero gap.
// ---------------------------------------------------------------------------
__global__ __launch_bounds__(256) void k0_prep(
    const float* __restrict__ w1, const float* __restrict__ w2,
    const float* __restrict__ w0,
    US* __restrict__ wt1, US* __restrict__ wt2,
    US* __restrict__ wt0, float* __restrict__ gap) {
  int gid = blockIdx.x * 256 + threadIdx.x;
  if (gid < 18432) {
    int e = gid;                              // w1 flat [oc][ic][ky][kx]
    int oc = e / 288, ic = (e / 9) % 32, ky = (e / 3) % 3, kx = e % 3;
    wt1[((ky * 3 + kx) * 64 + oc) * 32 + ic] = f2bf(w1[e]);
  } else if (gid < 18432 + 8192) {
    int e = gid - 18432;
    wt2[e] = f2bf(w2[e]);
  } else if (gid < 18432 + 8192 + 1024) {
    int e = gid - (18432 + 8192);             // e = oc*32 + k
    int oc = e >> 5, k = e & 31;
    wt0[e] = (k < 27) ? f2bf(w0[oc * 27 + k]) : (US)0;
  } else if (gid < 18432 + 8192 + 1024 + 8192) {
    gap[gid - (18432 + 8192 + 1024)] = 0.f;
  }
}

// ---------------------------------------------------------------------------
// K12 (R17): FULLY FUSED stem conv1 + conv2 + conv3 + BN/ReLU + GAP.
// Persistent blocks: grid (8,64) = 512 = 2/CU. Each block owns 7-8 conv2
// output rows of one n. Three LDS regions:
//   xr: x-ring, 6 slots x 3ch x 256 f32 (18432 B), staged via global_load_lds
//       (wave-uniform slot per 64-chunk group; lanes>=60 masked so pad cols
//        0-3 / 244-255 stay zero).
//   st: h1 ring, 6 slots x 4096 US (49152 B), parity-split row layout with
//       XOR swizzle (US units: uo ^ ((uo>>6)&7)<<3), written by the in-LDS
//       stem (ds_write, px<120 guard keeps pad cells zero), read by conv2.
//   tile: conv2 output [64px][72] bf16 (9216 B).
// Per iteration y: stage x rows 4y+4..4y+7 (async) -> conv2 rows 2y..2y+2
// (18 MFMA) -> barrier (covers vmcnt) -> stem builds h1 rows 2y+2,2y+3 for
// the next iteration (2 waves/row, 2 tiles/wave) -> conv3 + GAP -> barrier.
// h1 intermediate never touches HBM; k1 kernel eliminated.
// Stem math is bit-identical to old k1 (same fragments/MFMA/BN/bf16).
// ---------------------------------------------------------------------------
#define TS 72
__device__ __forceinline__ void gld_lds16(const void* g, void* l) {
  __builtin_amdgcn_global_load_lds(
      (const __attribute__((address_space(1))) unsigned int*)g,
      (__attribute__((address_space(3))) unsigned int*)l, 16, 0, 0);
}

// Build one 32-px stem tile of h1 row gy into slot (gy+1)%6 of st.
__device__ __forceinline__ void stem_tile(
    const float* xr, US* st, int gy, int tb, int lane31, int half,
    bf16x8 sb0, bf16x8 sb1, float al0, float be0) {
  int px = tb + lane31;
  int oxc = px < H1_ ? px : (H1_ - 1);
  // x-ring slots for the 3 input rows (iy = 2gy-1+ky; iy=-1 -> zero slot 5)
  int sl[3];
#pragma unroll
  for (int ky = 0; ky < 3; ky++) sl[ky] = (2 * gy - 1 + ky + 6) % 6;
  float fa[16];
#pragma unroll
  for (int m = 0; m < 2; m++)
#pragma unroll
    for (int j = 0; j < 8; j++) {
      int k = m * 16 + half * 8 + j;
      float v = 0.f;
      if (k < 27) {
        int ic = k / 9, rem = k - ic * 9;
        int ky = rem / 3, kx = rem - ky * 3;
        v = xr[sl[ky] * 768 + ic * 256 + 3 + 2 * oxc + kx];
      }
      fa[m * 8 + j] = v;
    }
  bf16x8 a0, a1;
#pragma unroll
  for (int j = 0; j < 8; j++) {
    a0[j] = (short)f2bf(fa[j]);
    a1[j] = (short)f2bf(fa[8 + j]);
  }
  f32x16 acc;
#pragma unroll
  for (int i = 0; i < 16; i++) acc[i] = 0.f;
  acc = __builtin_amdgcn_mfma_f32_32x32x16_bf16(a0, sb0, acc, 0, 0, 0);
  acc = __builtin_amdgcn_mfma_f32_32x32x16_bf16(a1, sb1, acc, 0, 0, 0);
  int r6 = ((gy + 1) % 6) * 4096;
#pragma unroll
  for (int r = 0; r < 16; r++) {
    int row = (r & 3) + 8 * (r >> 2) + 4 * half;
    int pxo = tb + row;
    if (pxo < H1_) {                       // keep pad cells zero
      int pl = pxo & 1, mm = (pxo + 1) >> 1;
      int uo = pl * 1984 + mm * 32 + lane31;
      int us = uo ^ (((uo >> 6) & 7) << 3);
      st[r6 + us] = f2bf(fmaxf(fmaf(acc[r], al0, be0), 0.f));
    }
  }
}

__global__ __launch_bounds__(256, 2) void k12_fused(
    const float* __restrict__ x, const US* __restrict__ wt0,
    const US* __restrict__ wt1, const US* __restrict__ wt2,
    const float* __restrict__ a0p, const float* __restrict__ b0p,
    const float* __restrict__ a1, const float* __restrict__ b1,
    const float* __restrict__ a2, const float* __restrict__ b2,
    float* __restrict__ gap) {
  __shared__ __align__(16) US st[6 * 4096];      // 49152 B h1 ring (swz)
  __shared__ __align__(16) float xr[6 * 768];    // 18432 B x ring
  __shared__ __align__(16) US tile[64 * TS];     // 9216 B conv2 out
  int t = threadIdx.x, w = t >> 6, l = t & 63;
  int lane31 = l & 31, half = l >> 5;

  // XCD x (= blockIdx.x, x-major dispatch) handles n in [8x, 8x+8)
  int n = 8 * blockIdx.x + (blockIdx.y & 7);
  int bxr = blockIdx.y >> 3;                     // row-group 0..7
  int ny = bxr < 4 ? 8 : 7;
  int y0 = bxr < 4 ? bxr * 8 : 32 + (bxr - 4) * 7;

  const float* xn = x + (long)n * C0_ * HW_ * HW_;

  // ---- hoisted weights / BN params (loop-invariant, registers) ----
  int wm = w & 1, wn = w >> 1;                   // conv2 roles
  int oc = wn * 32 + lane31;
  int pt = w & 1, og = w >> 1;                   // conv3 roles
  const US* wb = wt0 + lane31 * 32 + half * 8;   // stem B frags (oc=lane31)
  bf16x8 sb0 = *(const bf16x8*)(wb);
  bf16x8 sb1 = *(const bf16x8*)(wb + 16);
  float al0 = a0p[lane31], be0 = b0p[lane31];
  bf16x8 wA[9][2];
#pragma unroll
  for (int kk = 0; kk < 9; kk++)
#pragma unroll
    for (int c = 0; c < 2; c++)
      wA[kk][c] = *(const bf16x8*)(wt1 + (kk * 64 + oc) * 32 + half * 8 + c * 16);
  bf16x8 wB[2][4];
  float al2[2], be2[2];
#pragma unroll
  for (int nt = 0; nt < 2; nt++) {
    int oc2 = (og * 2 + nt) * 32 + lane31;
#pragma unroll
    for (int c = 0; c < 4; c++)
      wB[nt][c] = *(const bf16x8*)(wt2 + oc2 * 64 + half * 8 + c * 16);
    al2[nt] = a2[oc2]; be2[nt] = b2[oc2];
  }
  float al1 = a1[oc], be1 = b1[oc];

  // conv2 A-read offsets (swizzled, within-slot US units)
  int px2 = wm * 32 + lane31;
  int xx = px2 < 60 ? px2 : 59;
  int abase = xx * 32 + half * 8;
  int usofs[3][2];
#pragma unroll
  for (int kx = 0; kx < 3; kx++)
#pragma unroll
    for (int c = 0; c < 2; c++) {
      int uo = (kx == 1 ? 0 : (kx == 0 ? 1984 : 2016)) + abase + c * 16;
      usofs[kx][c] = uo ^ (((uo >> 6) & 7) << 3);
    }

  // ---- prologue: zero LDS (pads stay zero forever) ----
  {
    uint4 z; z.x = z.y = z.z = z.w = 0u;
    for (int e = t; e < 4224; e += 256) {
      if (e < 3072) ((uint4*)st)[e] = z;
      else          ((uint4*)xr)[e - 3072] = z;
    }
  }
  __syncthreads();
  // pass1: stage x rows 4y0-3..4y0+1 (skip iy<0)
  {
    int r0 = 4 * y0 - 3;
#pragma unroll
    for (int i = 0; i < 4; i++) {
      int c = i * 256 + t;
      if (c < 960) {                         // 15 rowch (wave-uniform)
        int rc = c >> 6;
        int iy = r0 + rc / 3, ic = rc - (rc / 3) * 3;
        if (iy >= 0 && (t & 63) < 60)
          gld_lds16((const char*)(xn + (long)ic * HW_ * HW_ + (long)iy * HW_) +
                        (t & 63) * 16,
                    (char*)xr + ((iy % 6) * 768 + ic * 256) * 4 + 16 +
                        (t & 63) * 16);
      }
    }
  }
  __syncthreads();
  // stem: h1 rows 2y0-1, 2y0 (all 4 waves, one 32-px tile each)
  for (int j = 0; j < 2; j++) {
    int gy = 2 * y0 - 1 + j;
    if (gy >= 0)
      stem_tile(xr, st, gy, w * 32, lane31, half, sb0, sb1, al0, be0);
  }
  __syncthreads();
  // pass2: stage x rows 4y0+2, 4y0+3
  {
    int r0 = 4 * y0 + 2;
#pragma unroll
    for (int i = 0; i < 2; i++) {
      int c = i * 256 + t;
      if (c < 384) {                         // 6 rowch
        int rc = c >> 6;
        int iy = r0 + rc / 3, ic = rc - (rc / 3) * 3;
        if ((t & 63) < 60)
          gld_lds16((const char*)(xn + (long)ic * HW_ * HW_ + (long)iy * HW_) +
                        (t & 63) * 16,
                    (char*)xr + ((iy % 6) * 768 + ic * 256) * 4 + 16 +
                        (t & 63) * 16);
      }
    }
  }
  __syncthreads();
  // stem: h1 row 2y0+1
  stem_tile(xr, st, 2 * y0 + 1, w * 32, lane31, half, sb0, sb1, al0, be0);
  __syncthreads();

  // ---- main loop over conv2 output rows ----
  for (int it = 0; it < ny; ++it) {
    int y = y0 + it;
    bool more = (it + 1 < ny);
    // (a) async stage x rows 4y+4..4y+7 (covered by conv2 until barrier)
    if (more) {
      int r0 = 4 * y + 4;
#pragma unroll
      for (int i = 0; i < 3; i++) {
        int c = i * 256 + t;                 // 12 rowch exactly
        int rc = c >> 6;
        int iy = r0 + rc / 3, ic = rc - (rc / 3) * 3;
        if ((t & 63) < 60)
          gld_lds16((const char*)(xn + (long)ic * HW_ * HW_ + (long)iy * HW_) +
                        (t & 63) * 16,
                    (char*)xr + ((iy % 6) * 768 + ic * 256) * 4 + 16 +
                        (t & 63) * 16);
      }
    }
    // (b) conv2 3x3 s2 on h1 rows 2y..2y+2
    f32x16 acc;
#pragma unroll
    for (int i = 0; i < 16; i++) acc[i] = 0.f;
#pragma unroll
    for (int ky = 0; ky < 3; ky++) {
      int r = 2 * y + ky;
      int sb6 = (r % 6) * 4096;
#pragma unroll
      for (int kx = 0; kx < 3; kx++) {
#pragma unroll
        for (int c = 0; c < 2; c++) {
          bf16x8 av = *(const bf16x8*)(st + sb6 + usofs[kx][c]);
          acc = __builtin_amdgcn_mfma_f32_32x32x16_bf16(av, wA[ky * 3 + kx][c],
                                                        acc, 0, 0, 0);
        }
      }
    }
#pragma unroll
    for (int r = 0; r < 16; r++) {
      int row = (r & 3) + 8 * (r >> 2) + 4 * half;
      tile[(wm * 32 + row) * TS + oc] = f2bf(fmaxf(fmaf(acc[r], al1, be1), 0.f));
    }
    __syncthreads();   // tile ready; drains x-stage vmcnt (conv2 as cover)

    // (d) stem: build h1 rows 2y+2, 2y+3 for next iteration
    if (more) {
      int gy = 2 * y + 2 + (w >> 1);         // 2 waves per row
      int ws = w & 1;
      stem_tile(xr, st, gy, ws * 32, lane31, half, sb0, sb1, al0, be0);
      stem_tile(xr, st, gy, 64 + ws * 32, lane31, half, sb0, sb1, al0, be0);
    }

    // (e) conv3 1x1 64->128 + BN/ReLU + GAP
    const US* ab = tile + (pt * 32 + lane31) * TS + half * 8;
    bf16x8 af[4];
#pragma unroll
    for (int c = 0; c < 4; c++) af[c] = *(const bf16x8*)(ab + c * 16);
#pragma unroll
    for (int nt = 0; nt < 2; nt++) {
      int oc2 = (og * 2 + nt) * 32 + lane31;
      f32x16 acc2;
#pragma unroll
      for (int i = 0; i < 16; i++) acc2[i] = 0.f;
#pragma unroll
      for (int c = 0; c < 4; c++)
        acc2 = __builtin_amdgcn_mfma_f32_32x32x16_bf16(af[c], wB[nt][c], acc2,
                                                       0, 0, 0);
      float s = 0.f;
      if (pt == 0) {
#pragma unroll
        for (int r = 0; r < 16; r++) s += fmaxf(fmaf(acc2[r], al2[nt], be2[nt]), 0.f);
      } else {
#pragma unroll
        for (int r = 0; r < 16; r++) {
          int row = (r & 3) + 8 * (r >> 2) + 4 * half;
          if (32 + row < 60) s += fmaxf(fmaf(acc2[r], al2[nt], be2[nt]), 0.f);
        }
      }
      s += __shfl_xor(s, 32);
      if (half == 0) atomicAdd(gap + n * C3_ + oc2, s);
    }
    __syncthreads();   // protect tile + ring slots for next iteration
  }
}

// ---------------------------------------------------------------------------
// K4: head — 8 n's per block, wh reused (R15, passing). grid (5, 8).
// ---------------------------------------------------------------------------
__global__ __launch_bounds__(256) void k4_head(
    const float* __restrict__ gap, const float* __restrict__ wh,
    const float* __restrict__ alpha, const float* __restrict__ beta,
    float* __restrict__ out) {
  __shared__ float g[8 * C3_];
  int n0 = blockIdx.y * 8;
  int t = threadIdx.x;
  for (int e = t; e < 8 * C3_; e += 256)
    g[e] = gap[n0 * C3_ + e] * (1.f / 3600.f);
  __syncthreads();
  int o = blockIdx.x * 256 + t;
  const float* wr = wh + (long)o * C3_;
  float acc[8];
#pragma unroll
  for (int i = 0; i < 8; i++) acc[i] = 0.f;
#pragma unroll 4
  for (int c = 0; c < C3_; c += 4) {
    float4 wv = *(const float4*)(wr + c);
#pragma unroll
    for (int i = 0; i < 8; i++) {
      const float* gi = g + i * C3_ + c;
      acc[i] = fmaf(wv.x, gi[0], acc[i]);
      acc[i] = fmaf(wv.y, gi[1], acc[i]);
      acc[i] = fmaf(wv.z, gi[2], acc[i]);
      acc[i] = fmaf(wv.w, gi[3], acc[i]);
    }
  }
  float al = alpha[o], be = beta[o];
#pragma unroll
  for (int i = 0; i < 8; i++)
    out[(n0 + i) * HEAD_ + o] = fmaxf(fmaf(acc[i], al, be), 0.f);
}

// ---------------------------------------------------------------------------
extern "C" void kernel_launch(void* const* d_in, const int* in_sizes, int n_in,
                              void* d_out, int out_size, void* d_ws,
                              size_t ws_size, hipStream_t stream) {
  const float* x      = (const float*)d_in[0];
  const float* w_stem = (const float*)d_in[1];
  const float* a_stem = (const float*)d_in[2];
  const float* b_stem = (const float*)d_in[3];
  const float* w1     = (const float*)d_in[4];
  const float* a1     = (const float*)d_in[5];
  const float* b1     = (const float*)d_in[6];
  const float* w2     = (const float*)d_in[7];
  const float* a2     = (const float*)d_in[8];
  const float* b2     = (const float*)d_in[9];
  const float* wh     = (const float*)d_in[10];
  const float* ah     = (const float*)d_in[11];
  const float* bh     = (const float*)d_in[12];
  float* out = (float*)d_out;

  US* wt1 = (US*)d_ws;                                   // 9*64*32
  US* wt2 = wt1 + 9 * 64 * 32;                           // 128*64
  US* wt0 = wt2 + C3_ * C2_;                             // 32*32
  float* gap = (float*)(wt0 + 1024);                     // 64*128 f32

  {  // K0 weight prep
    int total = 18432 + 8192 + 1024 + 8192;              // 35840
    k0_prep<<<(total + 255) / 256, 256, 0, stream>>>(w1, w2, w_stem,
                                                     wt1, wt2, wt0, gap);
  }
  {  // K12 fully fused conv1+conv2+conv3+GAP
    dim3 grid(8, N_);
    k12_fused<<<grid, 256, 0, stream>>>(x, wt0, wt1, wt2, a_stem, b_stem,
                                        a1, b1, a2, b2, gap);
  }
  {  // K4 head
    dim3 grid(HEAD_ / 256, 8);
    k4_head<<<grid, 256, 0, stream>>>(gap, wh, ah, bh, out);
  }
}

// Round 5
// 148.745 us; speedup vs baseline: 1.1279x; 1.1279x over previous
//
#include <hip/hip_runtime.h>

#define N_    64
#define HW_   240
#define H1_   120
#define H2_   60
#define C0_   3
#define C1_   32
#define C2_   64
#define C3_   128
#define HEAD_ 1280

typedef unsigned short US;
typedef short bf16x8 __attribute__((ext_vector_type(8)));
typedef float f32x16 __attribute__((ext_vector_type(16)));

__device__ __forceinline__ US f2bf(float f) {
  union { float f; unsigned u; } v; v.f = f;
  unsigned r = v.u + 0x7FFF + ((v.u >> 16) & 1);  // RNE
  return (US)(r >> 16);
}

// h1q parity-split padded NHWC bf16: [n][row 122][parity 2][xh 62][32ch].
// h1 pixel (gy,gx): row = gy+1; gx even=2m -> plane0[m]; gx odd=2m-1 -> plane1[m].
#define H1Q_ROW 3968
#define H1Q_PL  1984

__device__ __forceinline__ void gld_lds16(const void* g, void* l) {
  __builtin_amdgcn_global_load_lds(
      (const __attribute__((address_space(1))) unsigned int*)g,
      (__attribute__((address_space(3))) unsigned int*)l, 16, 0, 0);
}

// ---------------------------------------------------------------------------
// K0: prep — zero h1q pad cells (uint4); w1 -> wt1 [ky][kx][oc][ic] bf16;
// w2 -> wt2 [oc][ic] bf16; w_stem -> wt0 [oc][k32] bf16 (k>=27 zero);
// zero gap. (R16, unchanged.)
// ---------------------------------------------------------------------------
#define ZCHN   368                 // zero-chunks per n (124+124+120)
#define ZTOT   (64 * ZCHN * 4)     // 94208
__global__ __launch_bounds__(256) void k0_prep(
    const float* __restrict__ w1, const float* __restrict__ w2,
    const float* __restrict__ w0,
    US* __restrict__ h1q, US* __restrict__ wt1, US* __restrict__ wt2,
    US* __restrict__ wt0, float* __restrict__ gap) {
  int gid = blockIdx.x * 256 + threadIdx.x;
  if (gid < ZTOT) {
    int c = gid >> 2, q = gid & 3;
    int n = c / ZCHN, cc = c % ZCHN;
    long off; int y;
    if (cc < 124)      { y = 0;   off = (long)cc * 32; }
    else if (cc < 248) { y = 121; off = (long)(cc - 124) * 32; }
    else               { y = cc - 247; off = H1Q_PL; }   // p1 m=0, rows 1..120
    uint4 z; z.x = z.y = z.z = z.w = 0u;
    *(uint4*)(h1q + ((long)(n * 122 + y)) * H1Q_ROW + off + q * 8) = z;
  } else if (gid < ZTOT + 18432) {
    int e = gid - ZTOT;                       // w1 flat [oc][ic][ky][kx]
    int oc = e / 288, ic = (e / 9) % 32, ky = (e / 3) % 3, kx = e % 3;
    wt1[((ky * 3 + kx) * 64 + oc) * 32 + ic] = f2bf(w1[e]);
  } else if (gid < ZTOT + 18432 + 8192) {
    int e = gid - (ZTOT + 18432);
    wt2[e] = f2bf(w2[e]);
  } else if (gid < ZTOT + 18432 + 8192 + 1024) {
    int e = gid - (ZTOT + 18432 + 8192);      // e = oc*32 + k
    int oc = e >> 5, k = e & 31;
    wt0[e] = (k < 27) ? f2bf(w0[oc * 27 + k]) : (US)0;
  } else if (gid < ZTOT + 18432 + 8192 + 1024 + 8192) {
    gap[gid - (ZTOT + 18432 + 8192 + 1024)] = 0.f;
  }
}

// ---------------------------------------------------------------------------
// K1 (R18): stem conv 3->32 via MFMA im2col. R12 structure (1 row/block,
// grid 120x64). Only change vs R16: x staging now uses global_load_lds
// (wave-uniform seg per wave, lanes 0..59 active, lane0 always active ->
// correct LDS base; iy<0 rows pre-zeroed block-uniformly at y==0). Removes
// the flat_load->VGPR->ds_write round-trip (540 float4) and its addr VALU.
// Values staged are bit-identical to R16.
// ---------------------------------------------------------------------------
#define XSW 248
__global__ __launch_bounds__(256) void k1_mfma(
    const float* __restrict__ x, const US* __restrict__ wt0,
    const float* __restrict__ alpha, const float* __restrict__ beta,
    US* __restrict__ h1q) {
  __shared__ __align__(16) float xs[3 * 3 * XSW];  // [seg=ic*3+r][248]
  __shared__ US ot[128 * 32];         // [px][oc] bf16
  int y = blockIdx.x, n = blockIdx.y;
  int iy0 = 2 * y - 1;
  const float* xn = x + (long)n * C0_ * HW_ * HW_;
  int t = threadIdx.x, w = t >> 6, l = t & 63;

  // boundary zeros: cols 0..3 and 244..247 per seg
  if (t < 18) {
    int seg = t >> 1, end = t & 1;
    float4 z; z.x = z.y = z.z = z.w = 0.f;
    *(float4*)(xs + seg * XSW + (end ? 244 : 0)) = z;
  }
  // iy<0 rows (only y==0, segs r==0): pre-zero interior
  if (y == 0) {
    float4 z; z.x = z.y = z.z = z.w = 0.f;
    for (int e = t; e < 180; e += 256) {
      int m = e % 60, icz = e / 60;
      *(float4*)(xs + (icz * 3) * XSW + 4 + 4 * m) = z;
    }
  }
  __syncthreads();   // zeros visible before async staging overlaps

  // async stage: seg (wave-uniform) = w, w+4, w+8; 60 lanes x 16 B each
  for (int sgi = w; sgi < 9; sgi += 4) {
    int ic = sgi / 3, r = sgi - (sgi / 3) * 3;
    int iy = iy0 + r;                  // wave-uniform
    if (iy >= 0 && l < 60)
      gld_lds16((const char*)(xn + (long)ic * HW_ * HW_ + (long)iy * HW_) +
                    l * 16,
                (char*)(xs + sgi * XSW + 4) + l * 16);
  }
  __syncthreads();   // drains vmcnt

  int wv = w;
  int lane31 = l & 31, half = l >> 5;
  int ox = wv * 32 + lane31;
  int oxc = ox < H1_ ? ox : (H1_ - 1);

  // A fragments: k = m*16 + half*8 + j; value = xs[seg(k)][3 + 2*oxc + kx]
  float fa[16];
#pragma unroll
  for (int m = 0; m < 2; m++)
#pragma unroll
    for (int j = 0; j < 8; j++) {
      int k = m * 16 + half * 8 + j;
      float v = 0.f;
      if (k < 27) {
        int ic = k / 9, rem = k - ic * 9;
        int ky = rem / 3, kx = rem - ky * 3;
        v = xs[(ic * 3 + ky) * XSW + 3 + 2 * oxc + kx];
      }
      fa[m * 8 + j] = v;
    }
  bf16x8 a0, a1;
#pragma unroll
  for (int j = 0; j < 8; j++) {
    a0[j] = (short)f2bf(fa[j]);
    a1[j] = (short)f2bf(fa[8 + j]);
  }
  const US* wb = wt0 + lane31 * 32 + half * 8;   // oc = lane31
  bf16x8 b0 = *(const bf16x8*)(wb);
  bf16x8 b1 = *(const bf16x8*)(wb + 16);

  f32x16 acc;
#pragma unroll
  for (int i = 0; i < 16; i++) acc[i] = 0.f;
  acc = __builtin_amdgcn_mfma_f32_32x32x16_bf16(a0, b0, acc, 0, 0, 0);
  acc = __builtin_amdgcn_mfma_f32_32x32x16_bf16(a1, b1, acc, 0, 0, 0);

  int oc = lane31;
  float al = alpha[oc], be = beta[oc];
#pragma unroll
  for (int r = 0; r < 16; r++) {
    int row = (r & 3) + 8 * (r >> 2) + 4 * half;   // px within tile
    float v = fmaxf(fmaf(acc[r], al, be), 0.f);
    ot[(wv * 32 + row) * 32 + oc] = f2bf(v);
  }
  __syncthreads();

  // store 120 px * 64 B as parity-split full chunks; 480 uint4 total
  long rowb = ((long)(n * 122 + y + 1)) * H1Q_ROW;
  for (int u = t; u < 480; u += 256) {
    int px = u >> 2, q = u & 3;
    int pl = px & 1;
    int m = (px + 1) >> 1;
    long addr = rowb + (pl ? H1Q_PL : 0) + (long)m * 32 + q * 8;
    *(uint4*)(h1q + addr) = *(const uint4*)(ot + px * 32 + q * 8);
  }
}

// ---------------------------------------------------------------------------
// K2 (R16, unchanged — known good): persistent-row pipelined fused
// conv2+conv3+GAP. grid (8,64) = 512 blocks = 2/CU. LDS ring of 6 row-slots,
// 8192 B each; staging padded to 512 chunks (8 KB) per row (wave-uniform
// {row, slot}). All weights hoisted to registers; main loop has zero global
// loads.
// ---------------------------------------------------------------------------
#define TS 72
__global__ __launch_bounds__(256, 2) void k2_fused(
    const US* __restrict__ h1q, const US* __restrict__ wt1,
    const US* __restrict__ wt2,
    const float* __restrict__ a1, const float* __restrict__ b1,
    const float* __restrict__ a2, const float* __restrict__ b2,
    float* __restrict__ gap) {
  __shared__ __align__(16) US st[6 * 4096];    // 49152 B: 6 row-slots (swz)
  __shared__ __align__(16) US tile[64 * TS];   // 9216 B: conv2 out [px][oc]
  int t = threadIdx.x, w = t >> 6, l = t & 63;
  int lane31 = l & 31, half = l >> 5;

  // XCD x (= blockIdx.x, x-major dispatch) handles n in [8x, 8x+8)
  int n = 8 * blockIdx.x + (blockIdx.y & 7);
  int bxr = blockIdx.y >> 3;                   // row-group 0..7
  int ny = bxr < 4 ? 8 : 7;
  int y0 = bxr < 4 ? bxr * 8 : 32 + (bxr - 4) * 7;

  const char* nb = (const char*)(h1q + (long)(n * 122) * H1Q_ROW);

  // ---- hoist all weights / BN params to registers (loop-invariant) ----
  int wm = w & 1, wn = w >> 1;                 // stage-A roles
  int oc = wn * 32 + lane31;
  int pt = w & 1, og = w >> 1;                 // conv3 roles
  bf16x8 wA[9][2];
#pragma unroll
  for (int kk = 0; kk < 9; kk++)
#pragma unroll
    for (int c = 0; c < 2; c++)
      wA[kk][c] = *(const bf16x8*)(wt1 + (kk * 64 + oc) * 32 + half * 8 + c * 16);
  bf16x8 wB[2][4];
  float al2[2], be2[2];
#pragma unroll
  for (int nt = 0; nt < 2; nt++) {
    int oc2 = (og * 2 + nt) * 32 + lane31;
#pragma unroll
    for (int c = 0; c < 4; c++)
      wB[nt][c] = *(const bf16x8*)(wt2 + oc2 * 64 + half * 8 + c * 16);
    al2[nt] = a2[oc2]; be2[nt] = b2[oc2];
  }
  float al1 = a1[oc], be1 = b1[oc];

  // per-thread invariant A-read offsets (swizzled, within-row US units)
  int px = wm * 32 + lane31;
  int xx = px < 60 ? px : 59;
  int abase = xx * 32 + half * 8;
  int usofs[3][2];
#pragma unroll
  for (int kx = 0; kx < 3; kx++)
#pragma unroll
    for (int c = 0; c < 2; c++) {
      int uo = (kx == 1 ? 0 : (kx == 0 ? 1984 : 2016)) + abase + c * 16;
      usofs[kx][c] = uo ^ (((uo >> 6) & 7) << 3);
    }

  // ---- prologue: stage rows 2y0..2y0+2, 512 chunks (8 KB) per row ----
#pragma unroll
  for (int i = 0; i < 6; i++) {
    int c = i * 256 + t;                  // 1536 = 3 rows * 512 chunks
    int rw = c >> 9;                      // wave-uniform (512 % 64 == 0)
    int b = (c & 511) * 16;
    int sb = b ^ (((b >> 7) & 7) << 4);
    int r = 2 * y0 + rw;
    gld_lds16(nb + (long)r * 7936 + sb, (char*)st + (r % 6) * 8192 + b);
  }
  __syncthreads();

  for (int iy = 0; iy < ny; iy++) {
    int y = y0 + iy;
    // ---- issue next-2-row stage early (hidden under stage-A MFMAs) ----
    if (iy + 1 < ny) {
#pragma unroll
      for (int i = 0; i < 4; i++) {
        int c = i * 256 + t;              // 1024 = 2 rows * 512 chunks
        int rw = c >> 9;                  // wave-uniform
        int b = (c & 511) * 16;
        int sb = b ^ (((b >> 7) & 7) << 4);
        int r = 2 * y + 3 + rw;           // rows 2y+3, 2y+4 (slots disjoint
        gld_lds16(nb + (long)r * 7936 + sb,  // from compute rows 2y..2y+2)
                  (char*)st + (r % 6) * 8192 + b);
      }
    }

    // ---- stage A: conv2 3x3 s2, 32->64, from LDS ring ----
    f32x16 acc;
#pragma unroll
    for (int i = 0; i < 16; i++) acc[i] = 0.f;
#pragma unroll
    for (int ky = 0; ky < 3; ky++) {
      int r = 2 * y + ky;
      int sb6 = (r % 6) * 4096;
#pragma unroll
      for (int kx = 0; kx < 3; kx++) {
#pragma unroll
        for (int c = 0; c < 2; c++) {
          bf16x8 av = *(const bf16x8*)(st + sb6 + usofs[kx][c]);
          acc = __builtin_amdgcn_mfma_f32_32x32x16_bf16(av, wA[ky * 3 + kx][c],
                                                        acc, 0, 0, 0);
        }
      }
    }
#pragma unroll
    for (int r = 0; r < 16; r++) {
      int row = (r & 3) + 8 * (r >> 2) + 4 * half;
      tile[(wm * 32 + row) * TS + oc] = f2bf(fmaxf(fmaf(acc[r], al1, be1), 0.f));
    }
    __syncthreads();   // tile ready; also drains prefetch vmcnt (has cover)

    // ---- conv3 1x1 64->128 + BN/ReLU + GAP ----
    const US* ab = tile + (pt * 32 + lane31) * TS + half * 8;
    bf16x8 af[4];
#pragma unroll
    for (int c = 0; c < 4; c++) af[c] = *(const bf16x8*)(ab + c * 16);

#pragma unroll
    for (int nt = 0; nt < 2; nt++) {
      int oc2 = (og * 2 + nt) * 32 + lane31;
      f32x16 acc2;
#pragma unroll
      for (int i = 0; i < 16; i++) acc2[i] = 0.f;
#pragma unroll
      for (int c = 0; c < 4; c++)
        acc2 = __builtin_amdgcn_mfma_f32_32x32x16_bf16(af[c], wB[nt][c], acc2,
                                                       0, 0, 0);
      float s = 0.f;
      if (pt == 0) {
#pragma unroll
        for (int r = 0; r < 16; r++) s += fmaxf(fmaf(acc2[r], al2[nt], be2[nt]), 0.f);
      } else {
#pragma unroll
        for (int r = 0; r < 16; r++) {
          int row = (r & 3) + 8 * (r >> 2) + 4 * half;
          if (32 + row < 60) s += fmaxf(fmaf(acc2[r], al2[nt], be2[nt]), 0.f);
        }
      }
      s += __shfl_xor(s, 32);
      if (half == 0) atomicAdd(gap + n * C3_ + oc2, s);
    }
    __syncthreads();   // protect tile + ring slots for next iteration
  }
}

// ---------------------------------------------------------------------------
// K4 (R16, unchanged): head — 8 n's per block, wh reused. grid (5, 8).
// ---------------------------------------------------------------------------
__global__ __launch_bounds__(256) void k4_head(
    const float* __restrict__ gap, const float* __restrict__ wh,
    const float* __restrict__ alpha, const float* __restrict__ beta,
    float* __restrict__ out) {
  __shared__ float g[8 * C3_];
  int n0 = blockIdx.y * 8;
  int t = threadIdx.x;
  for (int e = t; e < 8 * C3_; e += 256)
    g[e] = gap[n0 * C3_ + e] * (1.f / 3600.f);
  __syncthreads();
  int o = blockIdx.x * 256 + t;
  const float* wr = wh + (long)o * C3_;
  float acc[8];
#pragma unroll
  for (int i = 0; i < 8; i++) acc[i] = 0.f;
#pragma unroll 4
  for (int c = 0; c < C3_; c += 4) {
    float4 wv = *(const float4*)(wr + c);
#pragma unroll
    for (int i = 0; i < 8; i++) {
      const float* gi = g + i * C3_ + c;
      acc[i] = fmaf(wv.x, gi[0], acc[i]);
      acc[i] = fmaf(wv.y, gi[1], acc[i]);
      acc[i] = fmaf(wv.z, gi[2], acc[i]);
      acc[i] = fmaf(wv.w, gi[3], acc[i]);
    }
  }
  float al = alpha[o], be = beta[o];
#pragma unroll
  for (int i = 0; i < 8; i++)
    out[(n0 + i) * HEAD_ + o] = fmaxf(fmaf(acc[i], al, be), 0.f);
}

// ---------------------------------------------------------------------------
extern "C" void kernel_launch(void* const* d_in, const int* in_sizes, int n_in,
                              void* d_out, int out_size, void* d_ws,
                              size_t ws_size, hipStream_t stream) {
  const float* x      = (const float*)d_in[0];
  const float* w_stem = (const float*)d_in[1];
  const float* a_stem = (const float*)d_in[2];
  const float* b_stem = (const float*)d_in[3];
  const float* w1     = (const float*)d_in[4];
  const float* a1     = (const float*)d_in[5];
  const float* b1     = (const float*)d_in[6];
  const float* w2     = (const float*)d_in[7];
  const float* a2     = (const float*)d_in[8];
  const float* b2     = (const float*)d_in[9];
  const float* wh     = (const float*)d_in[10];
  const float* ah     = (const float*)d_in[11];
  const float* bh     = (const float*)d_in[12];
  float* out = (float*)d_out;

  US* h1q = (US*)d_ws;                                   // 64*122*3968
  US* wt1 = h1q + (size_t)N_ * 122 * H1Q_ROW;            // 9*64*32
  US* wt2 = wt1 + 9 * 64 * 32;                           // 128*64
  US* wt0 = wt2 + C3_ * C2_;                             // 32*32
  float* gap = (float*)(wt0 + 1024);                     // 64*128 f32

  {  // K0 prep
    int total = ZTOT + 18432 + 8192 + 1024 + 8192;
    k0_prep<<<(total + 255) / 256, 256, 0, stream>>>(w1, w2, w_stem, h1q,
                                                     wt1, wt2, wt0, gap);
  }
  {  // K1 MFMA stem: one block per (row, n), gld_lds staging
    dim3 grid(H1_, N_);
    k1_mfma<<<grid, 256, 0, stream>>>(x, wt0, a_stem, b_stem, h1q);
  }
  {  // K2 persistent-row pipelined fused conv2+conv3+GAP
    dim3 grid(8, N_);
    k2_fused<<<grid, 256, 0, stream>>>(h1q, wt1, wt2, a1, b1, a2, b2, gap);
  }
  {  // K4: 8 n's per block, wh reused
    dim3 grid(HEAD_ / 256, 8);
    k4_head<<<grid, 256, 0, stream>>>(gap, wh, ah, bh, out);
  }
}